// Round 10
// baseline (141.487 us; speedup 1.0000x reference)
//
#include <hip/hip_runtime.h>
#include <stdint.h>
#include <stddef.h>

#define NN 4096
#define KK 1024
#define SPAN 4095u

typedef unsigned short ushort_t;
typedef __attribute__((ext_vector_type(8))) short short8v;   // 8 bf16 = 4 VGPR
typedef __attribute__((ext_vector_type(4))) float f32x4;     // MFMA C/D

// ---------------- Threefry-2x32, 20 rounds (exact JAX algorithm) -------------
__host__ __device__ inline void tf2x32(uint32_t k0, uint32_t k1,
                                       uint32_t x0, uint32_t x1,
                                       uint32_t* o0, uint32_t* o1) {
  uint32_t ks2 = k0 ^ k1 ^ 0x1BD11BDAu;
  uint32_t v0 = x0 + k0;
  uint32_t v1 = x1 + k1;
#define TF_ROT(x, r) (((x) << (r)) | ((x) >> (32 - (r))))
#define TF_RND(r) do { v0 += v1; v1 = TF_ROT(v1, r); v1 ^= v0; } while (0)
  TF_RND(13); TF_RND(15); TF_RND(26); TF_RND(6);
  v0 += k1;  v1 += ks2 + 1u;
  TF_RND(17); TF_RND(29); TF_RND(16); TF_RND(24);
  v0 += ks2; v1 += k0 + 2u;
  TF_RND(13); TF_RND(15); TF_RND(26); TF_RND(6);
  v0 += k0;  v1 += k1 + 3u;
  TF_RND(17); TF_RND(29); TF_RND(16); TF_RND(24);
  v0 += k1;  v1 += ks2 + 4u;
  TF_RND(13); TF_RND(15); TF_RND(26); TF_RND(6);
  v0 += ks2; v1 += k0 + 5u;
#undef TF_RND
#undef TF_ROT
  *o0 = v0; *o1 = v1;
}

__device__ inline uint32_t rb32(uint32_t ka, uint32_t kb, uint32_t i) {
  uint32_t a, b;
  tf2x32(ka, kb, 0u, i, &a, &b);
  return a ^ b;
}

// Monotone order-preserving float<->uint32 encoding; 0 == "no candidate".
__device__ inline uint32_t fenc(float f) {
  uint32_t b = __float_as_uint(f);
  return (b & 0x80000000u) ? ~b : (b | 0x80000000u);
}
__device__ inline float fdec(uint32_t e) {
  uint32_t b = (e & 0x80000000u) ? (e & 0x7FFFFFFFu) : ~e;
  return __uint_as_float(b);
}

__device__ inline ushort_t bf16rne(float f) {   // fp32 -> bf16 round-nearest-even
  uint32_t u = __float_as_uint(f);
  return (ushort_t)((u + 0x7FFFu + ((u >> 16) & 1u)) >> 16);
}

__device__ inline void glds16(const void* g, void* l) {
  __builtin_amdgcn_global_load_lds((const __attribute__((address_space(1))) void*)g,
                                   (__attribute__((address_space(3))) void*)l, 16, 0, 0);
}

// -------- Kernel 1: fused front-end: convert fp32->bf16 (+zero tables) -------
__global__ __launch_bounds__(256) void k_front(
    const float* __restrict__ X, const float* __restrict__ Y,
    ushort_t* __restrict__ Xb, ushort_t* __restrict__ Yb,
    uint32_t s0a, uint32_t s0b, uint32_t s1a, uint32_t s1b,
    uint32_t s2a, uint32_t s2b, uint32_t s3a, uint32_t s3b,
    uint32_t* __restrict__ rowmax, uint32_t* __restrict__ colmax,
    float* __restrict__ anchor, float* __restrict__ irr, float* __restrict__ irf,
    float* __restrict__ icr, float* __restrict__ icf) {
  const int b = blockIdx.x, tid = threadIdx.x;

  if (b < 4096) {
    if (b < 16) rowmax[b * 256 + tid] = 0u;
    else if (b < 32) colmax[(b - 16) * 256 + tid] = 0u;
    const float4* src = (const float4*)((b < 2048) ? X : Y);
    ushort4* dst = (ushort4*)((b < 2048) ? Xb : Yb);
    const int n4 = NN * KK / 4;
    for (int i = (b & 2047) * 256 + tid; i < n4; i += 2048 * 256) {
      float4 v = src[i];
      ushort4 o;
      o.x = bf16rne(v.x); o.y = bf16rne(v.y); o.z = bf16rne(v.z); o.w = bf16rne(v.w);
      dst[i] = o;
    }
    return;
  }

  // ---- dots part: one wave per row ----
  const int wid = tid >> 6;
  const int lane = tid & 63;
  const int row = (b - 4096) * 4 + wid;

  int jl = 0;
  if (lane < 4) {
    uint32_t ka = (lane == 0) ? s0a : (lane == 1) ? s1a : (lane == 2) ? s2a : s3a;
    uint32_t kb = (lane == 0) ? s0b : (lane == 1) ? s1b : (lane == 2) ? s2b : s3b;
    uint32_t k1a, k1b, k2a, k2b;
    tf2x32(ka, kb, 0u, 0u, &k1a, &k1b);
    tf2x32(ka, kb, 0u, 1u, &k2a, &k2b);
    uint32_t hi = rb32(k1a, k1b, (uint32_t)row);
    uint32_t lo = rb32(k2a, k2b, (uint32_t)row);
    uint32_t off = ((hi % SPAN) * 256u + (lo % SPAN)) % SPAN;
    int j = (int)off;
    jl = j + ((j >= row) ? 1 : 0);
  }
  const int j1r = __shfl(jl, 0), j1f = __shfl(jl, 1);
  const int j2r = __shfl(jl, 2), j2f = __shfl(jl, 3);

  const float4* xk = (const float4*)(X + (size_t)row * KK);
  const float4* yk = (const float4*)(Y + (size_t)row * KK);
  const float4* y1 = (const float4*)(Y + (size_t)j1r * KK);
  const float4* y2 = (const float4*)(Y + (size_t)j1f * KK);
  const float4* x1 = (const float4*)(X + (size_t)j2r * KK);
  const float4* x2 = (const float4*)(X + (size_t)j2f * KK);
  float sa = 0.f, s1 = 0.f, s2 = 0.f, s3 = 0.f, s4 = 0.f;
  for (int t = lane; t < KK / 4; t += 64) {
    float4 xv = xk[t], yv = yk[t], a1 = y1[t], a2 = y2[t], b1 = x1[t], b2 = x2[t];
    sa = fmaf(xv.x, yv.x, fmaf(xv.y, yv.y, fmaf(xv.z, yv.z, fmaf(xv.w, yv.w, sa))));
    s1 = fmaf(xv.x, a1.x, fmaf(xv.y, a1.y, fmaf(xv.z, a1.z, fmaf(xv.w, a1.w, s1))));
    s2 = fmaf(xv.x, a2.x, fmaf(xv.y, a2.y, fmaf(xv.z, a2.z, fmaf(xv.w, a2.w, s2))));
    s3 = fmaf(b1.x, yv.x, fmaf(b1.y, yv.y, fmaf(b1.z, yv.z, fmaf(b1.w, yv.w, s3))));
    s4 = fmaf(b2.x, yv.x, fmaf(b2.y, yv.y, fmaf(b2.z, yv.z, fmaf(b2.w, yv.w, s4))));
  }
  for (int m = 32; m >= 1; m >>= 1) {
    sa += __shfl_xor(sa, m);
    s1 += __shfl_xor(s1, m);
    s2 += __shfl_xor(s2, m);
    s3 += __shfl_xor(s3, m);
    s4 += __shfl_xor(s4, m);
  }
  if (lane == 0) {
    anchor[row] = sa; irr[row] = s1; irf[row] = s2; icr[row] = s3; icf[row] = s4;
  }
}

// -- Kernel 2: 256x256 GEMM, 4 WAVES x (128x128)/wave: 1.5x less LDS-read dup -
// DS-duplication theory: with 8 waves of 128x64, waves sharing wr/wc read
// IDENTICAL fragments -> 192 KB LDS-read/K-tile for 64 KB unique. 4 waves of
// 128x128 cuts Sum(M_w+N_w) 1536->1024 rows (128 KB), total LDS-pipe work
// (incl. glds writes) / 1.37. Price: acc=256 VGPR -> ~350 total, 1 wave/SIMD.
// Phase skeleton preserves r5's verified staging discipline: a buffer region
// is staged ONLY in a phase strictly after the phase containing its last read
// (all waves' reads complete before their trailing barrier).
__global__ __launch_bounds__(256, 1) void k_gemm4w(
    const ushort_t* __restrict__ A, const ushort_t* __restrict__ B,
    const float* __restrict__ anchor,
    uint32_t* __restrict__ rowmax, uint32_t* __restrict__ colmax) {
  __shared__ ushort_t AL[2][2][8192];   // [dbuf][half][128 rows x 64 k]
  __shared__ ushort_t BL[2][2][8192];

  const int tid = threadIdx.x;
  const int lane = tid & 63;
  const int w = tid >> 6, wr = w >> 1, wc = w & 1;   // 4 waves: 2M x 2N
  const int l15 = lane & 15, l4 = lane >> 4;

  // T1: XCD-aware bijective swizzle (256 blocks % 8 == 0)
  const int swz = (blockIdx.x & 7) * 32 + (blockIdx.x >> 3);
  const int bi = swz >> 4, bj = swz & 15;

  // staging: 256 threads; thread -> row strow=tid>>3 (0..31) + 32*i, slot tid&7
  const int strow = tid >> 3;
  const int scol = ((tid & 7) ^ (strow & 7)) * 8;
  const ushort_t* Ab0 = A + (size_t)(bi * 256 + strow) * KK + scol;
  const ushort_t* Ab1 = A + (size_t)(bi * 256 + 128 + strow) * KK + scol;
  const ushort_t* Bb0 = B + (size_t)(bj * 256 + strow) * KK + scol;
  const ushort_t* Bb1 = B + (size_t)(bj * 256 + 128 + strow) * KK + scol;

  const int ss0 = ((0 * 4 + l4) ^ (l15 & 7)) * 8;
  const int ss1 = ((1 * 4 + l4) ^ (l15 & 7)) * 8;

  f32x4 acc[8][8] = {};
  short8v Areg[8], B0r[4], B1r[4];

#define STAGE_A(DD, KT)                                                        \
  do {                                                                         \
    glds16(Ab0 + (size_t)0 * KK + (KT) * 64,   &AL[DD][0][0 * 2048 + tid * 8]);\
    glds16(Ab0 + (size_t)32 * KK + (KT) * 64,  &AL[DD][0][1 * 2048 + tid * 8]);\
    glds16(Ab0 + (size_t)64 * KK + (KT) * 64,  &AL[DD][0][2 * 2048 + tid * 8]);\
    glds16(Ab0 + (size_t)96 * KK + (KT) * 64,  &AL[DD][0][3 * 2048 + tid * 8]);\
    glds16(Ab1 + (size_t)0 * KK + (KT) * 64,   &AL[DD][1][0 * 2048 + tid * 8]);\
    glds16(Ab1 + (size_t)32 * KK + (KT) * 64,  &AL[DD][1][1 * 2048 + tid * 8]);\
    glds16(Ab1 + (size_t)64 * KK + (KT) * 64,  &AL[DD][1][2 * 2048 + tid * 8]);\
    glds16(Ab1 + (size_t)96 * KK + (KT) * 64,  &AL[DD][1][3 * 2048 + tid * 8]);\
  } while (0)
#define STAGE_B(DD, KT)                                                        \
  do {                                                                         \
    glds16(Bb0 + (size_t)0 * KK + (KT) * 64,   &BL[DD][0][0 * 2048 + tid * 8]);\
    glds16(Bb0 + (size_t)32 * KK + (KT) * 64,  &BL[DD][0][1 * 2048 + tid * 8]);\
    glds16(Bb0 + (size_t)64 * KK + (KT) * 64,  &BL[DD][0][2 * 2048 + tid * 8]);\
    glds16(Bb0 + (size_t)96 * KK + (KT) * 64,  &BL[DD][0][3 * 2048 + tid * 8]);\
    glds16(Bb1 + (size_t)0 * KK + (KT) * 64,   &BL[DD][1][0 * 2048 + tid * 8]);\
    glds16(Bb1 + (size_t)32 * KK + (KT) * 64,  &BL[DD][1][1 * 2048 + tid * 8]);\
    glds16(Bb1 + (size_t)64 * KK + (KT) * 64,  &BL[DD][1][2 * 2048 + tid * 8]);\
    glds16(Bb1 + (size_t)96 * KK + (KT) * 64,  &BL[DD][1][3 * 2048 + tid * 8]);\
  } while (0)

#define BAR() do { __builtin_amdgcn_s_barrier(); \
                   __builtin_amdgcn_sched_barrier(0); } while (0)
#define LGKM0() do { asm volatile("s_waitcnt lgkmcnt(0)" ::: "memory"); \
                     __builtin_amdgcn_sched_barrier(0); } while (0)
#define VM16BAR() do { asm volatile("s_waitcnt vmcnt(16)" ::: "memory"); \
                       __builtin_amdgcn_s_barrier(); \
                       __builtin_amdgcn_sched_barrier(0); } while (0)

  // frag reads: A row = m*16+l15 in half wr; B row = n*16+l15 in half wc
#define RD_A(D, KH)                                                            \
  do {                                                                         \
    _Pragma("unroll")                                                          \
    for (int q = 0; q < 8; ++q)                                                \
      Areg[q] = *(const short8v*)&AL[D][wr][(q * 16 + l15) * 64                \
                                            + ((KH) ? ss1 : ss0)];             \
  } while (0)
#define RD_B(RR, D, NB, KH)                                                    \
  do {                                                                         \
    _Pragma("unroll")                                                          \
    for (int n = 0; n < 4; ++n)                                                \
      RR[n] = *(const short8v*)&BL[D][wc][(((NB) * 4 + n) * 16 + l15) * 64     \
                                          + ((KH) ? ss1 : ss0)];               \
  } while (0)

#define MFMA1(a, b, c) c = __builtin_amdgcn_mfma_f32_16x16x32_bf16(a, b, c, 0, 0, 0)
  // 32 MFMA: all 8 m-frags x one B quad -> acc[:][NB*4 .. NB*4+3]
#define CL32(BR, NB)                                                           \
  do {                                                                         \
    __builtin_amdgcn_s_setprio(1);                                             \
    _Pragma("unroll")                                                          \
    for (int q = 0; q < 8; ++q) {                                              \
      MFMA1(Areg[q], BR[0], acc[q][(NB) * 4 + 0]);                             \
      MFMA1(Areg[q], BR[1], acc[q][(NB) * 4 + 1]);                             \
      MFMA1(Areg[q], BR[2], acc[q][(NB) * 4 + 2]);                             \
      MFMA1(Areg[q], BR[3], acc[q][(NB) * 4 + 3]);                             \
    }                                                                          \
    __builtin_amdgcn_s_setprio(0);                                             \
  } while (0)

  // K-tile phase group (buf D, next-tile KT staged into D at p4):
  // p1: A(kh0)+B0(kh0); p2: B1(kh0); p3: A(kh1)+B0(kh1)+B1(kh1) [all reads of
  // D done and drained by p3's trailing barrier]; p4: STAGE(D,KT) only.
#define KTILE(D, KT)                                                           \
  do {                                                                         \
    RD_A(D, 0); RD_B(B0r, D, 0, 0);                                            \
    BAR(); LGKM0();                                                            \
    CL32(B0r, 0);                                                              \
    BAR();                                                                     \
    RD_B(B1r, D, 1, 0);                                                        \
    BAR(); LGKM0();                                                            \
    CL32(B1r, 1);                                                              \
    BAR();                                                                     \
    RD_A(D, 1); RD_B(B0r, D, 0, 1); RD_B(B1r, D, 1, 1);                        \
    BAR(); LGKM0();                                                            \
    CL32(B0r, 0);                                                              \
    BAR();                                                                     \
    STAGE_B(D, KT); STAGE_A(D, KT);                                            \
    BAR();                                                                     \
    CL32(B1r, 1);                                                              \
    VM16BAR();                                                                 \
  } while (0)

  // prologue: stage tiles 0 (buf0) and 1 (buf1); wait tile 0's 16 loads
  STAGE_B(0, 0); STAGE_A(0, 0);
  STAGE_B(1, 1); STAGE_A(1, 1);
  asm volatile("s_waitcnt vmcnt(16)" ::: "memory");
  __builtin_amdgcn_s_barrier();
  __builtin_amdgcn_sched_barrier(0);

  for (int i = 0; i < 8; ++i) {
    const int kt2 = (2 * i + 2) & 15, kt3 = (2 * i + 3) & 15;  // wrap tail
    KTILE(0, kt2);
    KTILE(1, kt3);
  }

#undef KTILE
#undef CL32
#undef MFMA1
#undef RD_B
#undef RD_A
#undef VM16BAR
#undef LGKM0
#undef BAR
#undef STAGE_B
#undef STAGE_A

  // ---- epilogue: masked (strictly below anchor, off-diagonal) row/col max ----
  // C/D layout: col = lane&15, row = (lane>>4)*4 + reg
  const int rbase = bi * 256 + wr * 128;
  const int cbase = bj * 256 + wc * 128;

  float ar[32], ac[8];
#pragma unroll
  for (int m = 0; m < 8; ++m)
#pragma unroll
    for (int r = 0; r < 4; ++r)
      ar[m * 4 + r] = anchor[rbase + m * 16 + l4 * 4 + r];
#pragma unroll
  for (int n = 0; n < 8; ++n)
    ac[n] = anchor[cbase + n * 16 + l15];

  // row maxima: reduce over l15 (xor 1,2,4,8)
#pragma unroll
  for (int m = 0; m < 8; ++m) {
#pragma unroll
    for (int r = 0; r < 4; ++r) {
      const int rg = rbase + m * 16 + l4 * 4 + r;
      const float a = ar[m * 4 + r];
      uint32_t e = 0;
#pragma unroll
      for (int n = 0; n < 8; ++n) {
        const int cg = cbase + n * 16 + l15;
        float v = acc[m][n][r];
        if (v < a && rg != cg) { uint32_t fe = fenc(v); e = (fe > e) ? fe : e; }
      }
#pragma unroll
      for (int sh = 1; sh < 16; sh <<= 1) {
        uint32_t o = (uint32_t)__shfl_xor((int)e, sh, 64);
        e = (o > e) ? o : e;
      }
      if (l15 == 0 && e) atomicMax(&rowmax[rg], e);
    }
  }
  // col maxima: reduce over l4 (xor 16,32)
#pragma unroll
  for (int n = 0; n < 8; ++n) {
    const int cg = cbase + n * 16 + l15;
    const float a = ac[n];
    uint32_t e = 0;
#pragma unroll
    for (int m = 0; m < 8; ++m) {
#pragma unroll
      for (int r = 0; r < 4; ++r) {
        const int rg = rbase + m * 16 + l4 * 4 + r;
        float v = acc[m][n][r];
        if (v < a && rg != cg) { uint32_t fe = fenc(v); e = (fe > e) ? fe : e; }
      }
    }
    {
      uint32_t o = (uint32_t)__shfl_xor((int)e, 16, 64); e = (o > e) ? o : e;
      o = (uint32_t)__shfl_xor((int)e, 32, 64);          e = (o > e) ? o : e;
    }
    if (l4 == 0 && e) atomicMax(&colmax[cg], e);
  }
}

// ---------------- Kernel 3: hinge terms + mean -------------------------------
__global__ __launch_bounds__(256) void k_final(
    const float* __restrict__ anchor,
    const float* __restrict__ irr, const float* __restrict__ irf,
    const float* __restrict__ icr, const float* __restrict__ icf,
    const uint32_t* __restrict__ rowmax, const uint32_t* __restrict__ colmax,
    float* __restrict__ out) {
  float s = 0.f;
  for (int k = (int)threadIdx.x; k < NN; k += 256) {
    float a = anchor[k];
    float d1 = fmaxf(irr[k] - a + 1.0f, 0.f);
    uint32_t rm = rowmax[k];
    float imp2r = rm ? fdec(rm) : irf[k];
    float d2 = fmaxf(imp2r - a + 1.0f, 0.f);
    float e1 = fmaxf(icr[k] - a + 1.0f, 0.f);
    uint32_t cm = colmax[k];
    float imp2c = cm ? fdec(cm) : icf[k];
    float e2 = fmaxf(imp2c - a + 1.0f, 0.f);
    s += d1 + d2 + e1 + e2;
  }
  __shared__ float red[4];
  for (int m = 32; m >= 1; m >>= 1) s += __shfl_xor(s, m);
  if ((threadIdx.x & 63) == 0) red[threadIdx.x >> 6] = s;
  __syncthreads();
  if (threadIdx.x == 0) out[0] = (red[0] + red[1] + red[2] + red[3]) * (1.0f / NN);
}

// -----------------------------------------------------------------------------
extern "C" void kernel_launch(void* const* d_in, const int* in_sizes, int n_in,
                              void* d_out, int out_size, void* d_ws, size_t ws_size,
                              hipStream_t stream) {
  const float* X = (const float*)d_in[0];
  const float* Y = (const float*)d_in[1];
  float* out = (float*)d_out;

  char* ws = (char*)d_ws;
  float* anchor    = (float*)(ws + 0 * 16384);
  float* irr       = (float*)(ws + 1 * 16384);
  float* irf       = (float*)(ws + 2 * 16384);
  float* icr       = (float*)(ws + 3 * 16384);
  float* icf       = (float*)(ws + 4 * 16384);
  uint32_t* rowmax = (uint32_t*)(ws + 5 * 16384);
  uint32_t* colmax = (uint32_t*)(ws + 6 * 16384);
  ushort_t* Xb     = (ushort_t*)(ws + 256 * 1024);
  ushort_t* Yb     = Xb + (size_t)NN * KK;

  // subkeys = split(key(42), 4), partitionable: sk_i = threefry((0,42),(0,i))
  uint32_t sk[4][2];
  for (int i = 0; i < 4; ++i) tf2x32(0u, 42u, 0u, (uint32_t)i, &sk[i][0], &sk[i][1]);

  k_front<<<4096 + NN / 4, 256, 0, stream>>>(
      X, Y, Xb, Yb,
      sk[0][0], sk[0][1], sk[1][0], sk[1][1], sk[2][0], sk[2][1], sk[3][0], sk[3][1],
      rowmax, colmax, anchor, irr, irf, icr, icf);

  k_gemm4w<<<256, 256, 0, stream>>>(Xb, Yb, anchor, rowmax, colmax);

  k_final<<<1, 256, 0, stream>>>(anchor, irr, irf, icr, icf, rowmax, colmax, out);
}

// Round 11
// 88.761 us; speedup vs baseline: 1.5940x; 1.5940x over previous
//
#include <hip/hip_runtime.h>
#include <stdint.h>
#include <stddef.h>

#define NN 4096
#define KK 1024
#define SPAN 4095u

typedef unsigned short ushort_t;
typedef __attribute__((ext_vector_type(8))) short short8v;   // 8 bf16 = 4 VGPR
typedef __attribute__((ext_vector_type(4))) float f32x4;     // MFMA C/D

// ---------------- Threefry-2x32, 20 rounds (exact JAX algorithm) -------------
__host__ __device__ inline void tf2x32(uint32_t k0, uint32_t k1,
                                       uint32_t x0, uint32_t x1,
                                       uint32_t* o0, uint32_t* o1) {
  uint32_t ks2 = k0 ^ k1 ^ 0x1BD11BDAu;
  uint32_t v0 = x0 + k0;
  uint32_t v1 = x1 + k1;
#define TF_ROT(x, r) (((x) << (r)) | ((x) >> (32 - (r))))
#define TF_RND(r) do { v0 += v1; v1 = TF_ROT(v1, r); v1 ^= v0; } while (0)
  TF_RND(13); TF_RND(15); TF_RND(26); TF_RND(6);
  v0 += k1;  v1 += ks2 + 1u;
  TF_RND(17); TF_RND(29); TF_RND(16); TF_RND(24);
  v0 += ks2; v1 += k0 + 2u;
  TF_RND(13); TF_RND(15); TF_RND(26); TF_RND(6);
  v0 += k0;  v1 += k1 + 3u;
  TF_RND(17); TF_RND(29); TF_RND(16); TF_RND(24);
  v0 += k1;  v1 += ks2 + 4u;
  TF_RND(13); TF_RND(15); TF_RND(26); TF_RND(6);
  v0 += ks2; v1 += k0 + 5u;
#undef TF_RND
#undef TF_ROT
  *o0 = v0; *o1 = v1;
}

__device__ inline uint32_t rb32(uint32_t ka, uint32_t kb, uint32_t i) {
  uint32_t a, b;
  tf2x32(ka, kb, 0u, i, &a, &b);
  return a ^ b;
}

// Monotone order-preserving float<->uint32 encoding; 0 == "no candidate".
__device__ inline uint32_t fenc(float f) {
  uint32_t b = __float_as_uint(f);
  return (b & 0x80000000u) ? ~b : (b | 0x80000000u);
}
__device__ inline float fdec(uint32_t e) {
  uint32_t b = (e & 0x80000000u) ? (e & 0x7FFFFFFFu) : ~e;
  return __uint_as_float(b);
}

__device__ inline ushort_t bf16rne(float f) {   // fp32 -> bf16 round-nearest-even
  uint32_t u = __float_as_uint(f);
  return (ushort_t)((u + 0x7FFFu + ((u >> 16) & 1u)) >> 16);
}
__device__ inline float bf2f(ushort_t v) {
  return __uint_as_float(((uint32_t)v) << 16);
}

__device__ inline void glds16(const void* g, void* l) {
  __builtin_amdgcn_global_load_lds((const __attribute__((address_space(1))) void*)g,
                                   (__attribute__((address_space(3))) void*)l, 16, 0, 0);
}

// ---------------- Kernel 1: fp32->bf16 convert for X,Y + zero max tables -----
__global__ __launch_bounds__(256) void k_prep(
    const float4* __restrict__ X, const float4* __restrict__ Y,
    ushort4* __restrict__ Xb, ushort4* __restrict__ Yb,
    uint32_t* __restrict__ rowmax, uint32_t* __restrict__ colmax) {
  const int b = blockIdx.x, tid = threadIdx.x;
  if (b < 16) rowmax[b * 256 + tid] = 0u;
  else if (b < 32) colmax[(b - 16) * 256 + tid] = 0u;
  const float4* src = (b < 2048) ? X : Y;
  ushort4* dst = (b < 2048) ? Xb : Yb;
  const int n4 = NN * KK / 4;
  for (int i = (b & 2047) * 256 + tid; i < n4; i += 2048 * 256) {
    float4 v = src[i];
    ushort4 o;
    o.x = bf16rne(v.x); o.y = bf16rne(v.y); o.z = bf16rne(v.z); o.w = bf16rne(v.w);
    dst[i] = o;
  }
}

// --------- Kernel 2: anchors + 4 gathered imposter dots (bf16 inputs) --------
__global__ __launch_bounds__(256) void k_dots(
    const ushort_t* __restrict__ Xb, const ushort_t* __restrict__ Yb,
    uint32_t s0a, uint32_t s0b, uint32_t s1a, uint32_t s1b,
    uint32_t s2a, uint32_t s2b, uint32_t s3a, uint32_t s3b,
    float* __restrict__ anchor, float* __restrict__ irr, float* __restrict__ irf,
    float* __restrict__ icr, float* __restrict__ icf) {
  const int wid = threadIdx.x >> 6;
  const int lane = threadIdx.x & 63;
  const int row = blockIdx.x * 4 + wid;

  int jl = 0;
  if (lane < 4) {
    uint32_t ka = (lane == 0) ? s0a : (lane == 1) ? s1a : (lane == 2) ? s2a : s3a;
    uint32_t kb = (lane == 0) ? s0b : (lane == 1) ? s1b : (lane == 2) ? s2b : s3b;
    uint32_t k1a, k1b, k2a, k2b;
    tf2x32(ka, kb, 0u, 0u, &k1a, &k1b);
    tf2x32(ka, kb, 0u, 1u, &k2a, &k2b);
    uint32_t hi = rb32(k1a, k1b, (uint32_t)row);
    uint32_t lo = rb32(k2a, k2b, (uint32_t)row);
    uint32_t off = ((hi % SPAN) * 256u + (lo % SPAN)) % SPAN;
    int j = (int)off;
    jl = j + ((j >= row) ? 1 : 0);
  }
  const int j1r = __shfl(jl, 0), j1f = __shfl(jl, 1);
  const int j2r = __shfl(jl, 2), j2f = __shfl(jl, 3);

  const short8v* xk = (const short8v*)(Xb + (size_t)row * KK);
  const short8v* yk = (const short8v*)(Yb + (size_t)row * KK);
  const short8v* y1 = (const short8v*)(Yb + (size_t)j1r * KK);
  const short8v* y2 = (const short8v*)(Yb + (size_t)j1f * KK);
  const short8v* x1 = (const short8v*)(Xb + (size_t)j2r * KK);
  const short8v* x2 = (const short8v*)(Xb + (size_t)j2f * KK);
  float sa = 0.f, s1 = 0.f, s2 = 0.f, s3 = 0.f, s4 = 0.f;
  for (int t = lane; t < KK / 8; t += 64) {
    short8v xv = xk[t], yv = yk[t], a1 = y1[t], a2 = y2[t], b1 = x1[t], b2 = x2[t];
#pragma unroll
    for (int j = 0; j < 8; ++j) {
      float xf = bf2f((ushort_t)xv[j]), yf = bf2f((ushort_t)yv[j]);
      sa = fmaf(xf, yf, sa);
      s1 = fmaf(xf, bf2f((ushort_t)a1[j]), s1);
      s2 = fmaf(xf, bf2f((ushort_t)a2[j]), s2);
      s3 = fmaf(bf2f((ushort_t)b1[j]), yf, s3);
      s4 = fmaf(bf2f((ushort_t)b2[j]), yf, s4);
    }
  }
  for (int m = 32; m >= 1; m >>= 1) {
    sa += __shfl_xor(sa, m);
    s1 += __shfl_xor(s1, m);
    s2 += __shfl_xor(s2, m);
    s3 += __shfl_xor(s3, m);
    s4 += __shfl_xor(s4, m);
  }
  if (lane == 0) {
    anchor[row] = sa; irr[row] = s1; irf[row] = s2; icr[row] = s3; icf[row] = s4;
  }
}

// ------------- Kernel 3: 256x256 MFMA GEMM, 8-phase (best measured) ----------
// Consistently the fastest of 9 structurally distinct schedules (67.4-68.5 us,
// absmax 0.0). Plateau mechanism (r8-r10 analysis): at the effective clock
// this dispatch achieves, the LDS pipe (reads at 3x wave-sharing duplication
// + glds writes) covers ~70% of the cycle budget; the only duplication-
// reducing geometry (4 waves x 128x128) needs >256 acc VGPRs and spills (r10).
__global__ __launch_bounds__(512, 2) void k_gemm8p(
    const ushort_t* __restrict__ A, const ushort_t* __restrict__ B,
    const float* __restrict__ anchor,
    uint32_t* __restrict__ rowmax, uint32_t* __restrict__ colmax) {
  __shared__ ushort_t AL[2][2][8192];
  __shared__ ushort_t BL[2][2][8192];

  const int tid = threadIdx.x;
  const int lane = tid & 63;
  const int w = tid >> 6, wr = w >> 2, wc = w & 3;   // 8 waves: 2M x 4N
  const int l15 = lane & 15, l4 = lane >> 4;

  const int swz = (blockIdx.x & 7) * 32 + (blockIdx.x >> 3);
  const int bi = swz >> 4, bj = swz & 15;

  const int strow = tid >> 3;
  const int scol = ((tid & 7) ^ (strow & 7)) * 8;
  const ushort_t* Abase = A + (size_t)(bi * 256 + strow) * KK + scol;
  const ushort_t* Bbase = B + (size_t)(bj * 256 + strow) * KK + scol;

  const int ss0 = ((0 * 4 + l4) ^ (l15 & 7)) * 8;
  const int ss1 = ((1 * 4 + l4) ^ (l15 & 7)) * 8;
  const int bhalf = wc >> 1, brow0 = (wc & 1) * 64 + l15;

  f32x4 acc[8][4] = {};
  short8v Areg[4][2], B0r[2][2], B1r[2][2];

#define STAGE_A(DD, KT)                                                        \
  do {                                                                         \
    glds16(Abase + (size_t)0 * KK + (KT) * 64,   &AL[DD][0][tid * 8]);         \
    glds16(Abase + (size_t)64 * KK + (KT) * 64,  &AL[DD][0][4096 + tid * 8]);  \
    glds16(Abase + (size_t)128 * KK + (KT) * 64, &AL[DD][1][tid * 8]);         \
    glds16(Abase + (size_t)192 * KK + (KT) * 64, &AL[DD][1][4096 + tid * 8]);  \
  } while (0)
#define STAGE_B(DD, KT)                                                        \
  do {                                                                         \
    glds16(Bbase + (size_t)0 * KK + (KT) * 64,   &BL[DD][0][tid * 8]);         \
    glds16(Bbase + (size_t)64 * KK + (KT) * 64,  &BL[DD][0][4096 + tid * 8]);  \
    glds16(Bbase + (size_t)128 * KK + (KT) * 64, &BL[DD][1][tid * 8]);         \
    glds16(Bbase + (size_t)192 * KK + (KT) * 64, &BL[DD][1][4096 + tid * 8]);  \
  } while (0)

#define BAR() do { __builtin_amdgcn_s_barrier(); \
                   __builtin_amdgcn_sched_barrier(0); } while (0)
#define LGKM0() do { asm volatile("s_waitcnt lgkmcnt(0)" ::: "memory"); \
                     __builtin_amdgcn_sched_barrier(0); } while (0)
#define VM8BAR() do { asm volatile("s_waitcnt vmcnt(8)" ::: "memory"); \
                      __builtin_amdgcn_s_barrier(); \
                      __builtin_amdgcn_sched_barrier(0); } while (0)

#define MFMA1(a, b, c) c = __builtin_amdgcn_mfma_f32_16x16x32_bf16(a, b, c, 0, 0, 0)
#define CL16(MS, NS, BR)                                                       \
  do {                                                                         \
    __builtin_amdgcn_s_setprio(1);                                             \
    _Pragma("unroll")                                                          \
    for (int q = 0; q < 4; ++q) {                                              \
      MFMA1(Areg[q][0], BR[0][0], acc[(MS) * 4 + q][(NS) * 2]);                \
      MFMA1(Areg[q][0], BR[1][0], acc[(MS) * 4 + q][(NS) * 2 + 1]);            \
      MFMA1(Areg[q][1], BR[0][1], acc[(MS) * 4 + q][(NS) * 2]);                \
      MFMA1(Areg[q][1], BR[1][1], acc[(MS) * 4 + q][(NS) * 2 + 1]);            \
    }                                                                          \
    __builtin_amdgcn_s_setprio(0);                                             \
  } while (0)

#define LDA(D, M, KH) (*(const short8v*)&AL[D][wr][((M) * 16 + l15) * 64 + ((KH) ? ss1 : ss0)])
#define LDB(D, N, KH) (*(const short8v*)&BL[D][bhalf][(brow0 + (N) * 16) * 64 + ((KH) ? ss1 : ss0)])

  STAGE_B(0, 0); STAGE_A(0, 0);
  STAGE_B(1, 1); STAGE_A(1, 1);
  asm volatile("s_waitcnt vmcnt(8)" ::: "memory");
  __builtin_amdgcn_s_barrier();
  __builtin_amdgcn_sched_barrier(0);

  for (int i = 0; i < 8; ++i) {
    const int kt2 = (2 * i + 2) & 15, kt3 = (2 * i + 3) & 15;

#pragma unroll
    for (int q = 0; q < 4; ++q) { Areg[q][0] = LDA(0, q, 0); Areg[q][1] = LDA(0, q, 1); }
#pragma unroll
    for (int n = 0; n < 2; ++n) { B0r[n][0] = LDB(0, n, 0); B0r[n][1] = LDB(0, n, 1); }
    BAR(); LGKM0();
    CL16(0, 0, B0r);
    BAR();

#pragma unroll
    for (int n = 0; n < 2; ++n) { B1r[n][0] = LDB(0, n + 2, 0); B1r[n][1] = LDB(0, n + 2, 1); }
    BAR(); LGKM0();
    CL16(0, 1, B1r);
    BAR();

#pragma unroll
    for (int q = 0; q < 4; ++q) { Areg[q][0] = LDA(0, q + 4, 0); Areg[q][1] = LDA(0, q + 4, 1); }
    STAGE_B(0, kt2);
    BAR(); LGKM0();
    CL16(1, 1, B1r);
    BAR();

    STAGE_A(0, kt2);
    BAR(); LGKM0();
    CL16(1, 0, B0r);
    VM8BAR();

#pragma unroll
    for (int q = 0; q < 4; ++q) { Areg[q][0] = LDA(1, q, 0); Areg[q][1] = LDA(1, q, 1); }
#pragma unroll
    for (int n = 0; n < 2; ++n) { B0r[n][0] = LDB(1, n, 0); B0r[n][1] = LDB(1, n, 1); }
    BAR(); LGKM0();
    CL16(0, 0, B0r);
    BAR();

#pragma unroll
    for (int n = 0; n < 2; ++n) { B1r[n][0] = LDB(1, n + 2, 0); B1r[n][1] = LDB(1, n + 2, 1); }
    BAR(); LGKM0();
    CL16(0, 1, B1r);
    BAR();

#pragma unroll
    for (int q = 0; q < 4; ++q) { Areg[q][0] = LDA(1, q + 4, 0); Areg[q][1] = LDA(1, q + 4, 1); }
    STAGE_B(1, kt3);
    BAR(); LGKM0();
    CL16(1, 1, B1r);
    BAR();

    STAGE_A(1, kt3);
    BAR(); LGKM0();
    CL16(1, 0, B0r);
    VM8BAR();
  }

#undef LDA
#undef LDB
#undef CL16
#undef MFMA1
#undef VM8BAR
#undef LGKM0
#undef BAR
#undef STAGE_A
#undef STAGE_B

  // ---- epilogue: masked (strictly below anchor, off-diagonal) row/col max ----
  // C/D layout: col = lane&15, row = (lane>>4)*4 + reg
  const int rbase = bi * 256 + wr * 128;
  const int cbase = bj * 256 + wc * 64;

  float ar[32], ac[4];
#pragma unroll
  for (int m = 0; m < 8; ++m)
#pragma unroll
    for (int r = 0; r < 4; ++r)
      ar[m * 4 + r] = anchor[rbase + m * 16 + l4 * 4 + r];
#pragma unroll
  for (int n = 0; n < 4; ++n)
    ac[n] = anchor[cbase + n * 16 + l15];

#pragma unroll
  for (int m = 0; m < 8; ++m) {
#pragma unroll
    for (int r = 0; r < 4; ++r) {
      const int rg = rbase + m * 16 + l4 * 4 + r;
      const float a = ar[m * 4 + r];
      uint32_t e = 0;
#pragma unroll
      for (int n = 0; n < 4; ++n) {
        const int cg = cbase + n * 16 + l15;
        float v = acc[m][n][r];
        if (v < a && rg != cg) { uint32_t fe = fenc(v); e = (fe > e) ? fe : e; }
      }
#pragma unroll
      for (int sh = 1; sh < 16; sh <<= 1) {
        uint32_t o = (uint32_t)__shfl_xor((int)e, sh, 64);
        e = (o > e) ? o : e;
      }
      if (l15 == 0 && e) atomicMax(&rowmax[rg], e);
    }
  }
#pragma unroll
  for (int n = 0; n < 4; ++n) {
    const int cg = cbase + n * 16 + l15;
    const float a = ac[n];
    uint32_t e = 0;
#pragma unroll
    for (int m = 0; m < 8; ++m) {
#pragma unroll
      for (int r = 0; r < 4; ++r) {
        const int rg = rbase + m * 16 + l4 * 4 + r;
        float v = acc[m][n][r];
        if (v < a && rg != cg) { uint32_t fe = fenc(v); e = (fe > e) ? fe : e; }
      }
    }
    {
      uint32_t o = (uint32_t)__shfl_xor((int)e, 16, 64); e = (o > e) ? o : e;
      o = (uint32_t)__shfl_xor((int)e, 32, 64);          e = (o > e) ? o : e;
    }
    if (l4 == 0 && e) atomicMax(&colmax[cg], e);
  }
}

// ---------------- Kernel 4: hinge terms + mean -------------------------------
__global__ __launch_bounds__(256) void k_final(
    const float* __restrict__ anchor,
    const float* __restrict__ irr, const float* __restrict__ irf,
    const float* __restrict__ icr, const float* __restrict__ icf,
    const uint32_t* __restrict__ rowmax, const uint32_t* __restrict__ colmax,
    float* __restrict__ out) {
  float s = 0.f;
  for (int k = (int)threadIdx.x; k < NN; k += 256) {
    float a = anchor[k];
    float d1 = fmaxf(irr[k] - a + 1.0f, 0.f);
    uint32_t rm = rowmax[k];
    float imp2r = rm ? fdec(rm) : irf[k];
    float d2 = fmaxf(imp2r - a + 1.0f, 0.f);
    float e1 = fmaxf(icr[k] - a + 1.0f, 0.f);
    uint32_t cm = colmax[k];
    float imp2c = cm ? fdec(cm) : icf[k];
    float e2 = fmaxf(imp2c - a + 1.0f, 0.f);
    s += d1 + d2 + e1 + e2;
  }
  __shared__ float red[4];
  for (int m = 32; m >= 1; m >>= 1) s += __shfl_xor(s, m);
  if ((threadIdx.x & 63) == 0) red[threadIdx.x >> 6] = s;
  __syncthreads();
  if (threadIdx.x == 0) out[0] = (red[0] + red[1] + red[2] + red[3]) * (1.0f / NN);
}

// -----------------------------------------------------------------------------
extern "C" void kernel_launch(void* const* d_in, const int* in_sizes, int n_in,
                              void* d_out, int out_size, void* d_ws, size_t ws_size,
                              hipStream_t stream) {
  const float* X = (const float*)d_in[0];
  const float* Y = (const float*)d_in[1];
  float* out = (float*)d_out;

  char* ws = (char*)d_ws;
  float* anchor    = (float*)(ws + 0 * 16384);
  float* irr       = (float*)(ws + 1 * 16384);
  float* irf       = (float*)(ws + 2 * 16384);
  float* icr       = (float*)(ws + 3 * 16384);
  float* icf       = (float*)(ws + 4 * 16384);
  uint32_t* rowmax = (uint32_t*)(ws + 5 * 16384);
  uint32_t* colmax = (uint32_t*)(ws + 6 * 16384);
  ushort_t* Xb     = (ushort_t*)(ws + 256 * 1024);
  ushort_t* Yb     = Xb + (size_t)NN * KK;

  // subkeys = split(key(42), 4), partitionable: sk_i = threefry((0,42),(0,i))
  uint32_t sk[4][2];
  for (int i = 0; i < 4; ++i) tf2x32(0u, 42u, 0u, (uint32_t)i, &sk[i][0], &sk[i][1]);

  k_prep<<<4096, 256, 0, stream>>>((const float4*)X, (const float4*)Y,
                                   (ushort4*)Xb, (ushort4*)Yb, rowmax, colmax);

  k_dots<<<NN / 4, 256, 0, stream>>>(Xb, Yb,
      sk[0][0], sk[0][1], sk[1][0], sk[1][1], sk[2][0], sk[2][1], sk[3][0], sk[3][1],
      anchor, irr, irf, icr, icf);

  k_gemm8p<<<256, 512, 0, stream>>>(Xb, Yb, anchor, rowmax, colmax);

  k_final<<<1, 256, 0, stream>>>(anchor, irr, irf, icr, icf, rowmax, colmax, out);
}